// Round 1
// baseline (214.002 us; speedup 1.0000x reference)
//
#include <hip/hip_runtime.h>
#include <stdint.h>

#define S_LEN 4096
#define DMODEL 512
#define NHEAD 8
#define DK 64

typedef __attribute__((ext_vector_type(8))) short short8;
typedef __attribute__((ext_vector_type(4))) float f32x4;

__device__ __forceinline__ unsigned short f2bf(float f) {
    unsigned int u = __float_as_uint(f);
    u = (u + 0x7fffu + ((u >> 16) & 1u)) >> 16;
    return (unsigned short)u;
}

// ---------------- prep kernels ----------------

__global__ void cast_bf16_kernel(const float* __restrict__ in,
                                 unsigned short* __restrict__ out, int n4) {
    int i = blockIdx.x * blockDim.x + threadIdx.x;
    if (i >= n4) return;
    float4 v = reinterpret_cast<const float4*>(in)[i];
    ushort4 o;
    o.x = f2bf(v.x); o.y = f2bf(v.y); o.z = f2bf(v.z); o.w = f2bf(v.w);
    reinterpret_cast<ushort4*>(out)[i] = o;
}

// out[h][c][r] = in[h][r][c]  (bf16 transposed weights, BT layout)
__global__ void transpose_w_kernel(const float* __restrict__ in,
                                   unsigned short* __restrict__ out,
                                   int R, int C, int total) {
    int o = blockIdx.x * blockDim.x + threadIdx.x;
    if (o >= total) return;
    int h = o / (R * C);
    int rem = o - h * (R * C);
    int c = rem / R;
    int r = rem - c * R;
    out[o] = f2bf(in[h * R * C + r * C + c]);
}

__global__ void zero_kernel(float* z) { *z = 0.0f; }

// ---------------- QKV projection GEMM ----------------
// C[h][s][n] = sum_d emb[s][d] * W[h][d][n];  Q gets extra *0.125 (1/sqrt(64))
__global__ __launch_bounds__(256) void proj_gemm_kernel(
    const unsigned short* __restrict__ A,
    const unsigned short* __restrict__ WTq,
    const unsigned short* __restrict__ WTk,
    const unsigned short* __restrict__ WTv,
    unsigned short* __restrict__ Qo,
    unsigned short* __restrict__ Ko,
    unsigned short* __restrict__ Vo) {
    int tid = threadIdx.x;
    int w = tid >> 6, l = tid & 63;
    int l15 = l & 15, lg = l >> 4;
    int mb = blockIdx.x;
    int p = blockIdx.y >> 3, h = blockIdx.y & 7;
    const unsigned short* BT = (p == 0 ? WTq : p == 1 ? WTk : WTv) + h * (DK * DMODEL);
    unsigned short* C = (p == 0 ? Qo : p == 1 ? Ko : Vo) + h * (S_LEN * DK);
    float scale = (p == 0) ? 0.125f : 1.0f;
    int row_a = mb * 64 + w * 16 + l15;
    f32x4 acc[4] = {};
    for (int ks = 0; ks < DMODEL; ks += 32) {
        short8 a = *reinterpret_cast<const short8*>(A + row_a * DMODEL + ks + lg * 8);
#pragma unroll
        for (int nb = 0; nb < 4; ++nb) {
            short8 b = *reinterpret_cast<const short8*>(BT + (nb * 16 + l15) * DMODEL + ks + lg * 8);
            acc[nb] = __builtin_amdgcn_mfma_f32_16x16x32_bf16(a, b, acc[nb], 0, 0, 0);
        }
    }
    int row_c = mb * 64 + w * 16 + lg * 4;
#pragma unroll
    for (int nb = 0; nb < 4; ++nb)
#pragma unroll
        for (int r = 0; r < 4; ++r)
            C[(row_c + r) * DK + nb * 16 + l15] = f2bf(acc[nb][r] * scale);
}

// ---------------- fused attention (unnormalized) ----------------
// O[h][q][v] = sum_t exp(S[q][t]) * V[t][v];  Z += sum exp(S)
// 8 waves x 16 q-rows, t tiled by 64. K tile and V^T tile in LDS (XOR swizzle).
__global__ __launch_bounds__(512) void attn_kernel(
    const unsigned short* __restrict__ Qg,
    const unsigned short* __restrict__ Kg,
    const unsigned short* __restrict__ Vg,
    unsigned short* __restrict__ concat,
    float* __restrict__ Z) {
    __shared__ unsigned short lds[16384];  // K:[0,4096) Vt:[4096,8192) P: 8x1024
    int tid = threadIdx.x;
    int w = tid >> 6, l = tid & 63;
    int l15 = l & 15, lg = l >> 4;
    int qb = blockIdx.x, h = blockIdx.y;
    const unsigned short* Qh = Qg + h * (S_LEN * DK);
    const unsigned short* Kh = Kg + h * (S_LEN * DK);
    const unsigned short* Vh = Vg + h * (S_LEN * DK);
    int qr0 = qb * 128 + w * 16;
    short8 aq[2];
#pragma unroll
    for (int ks = 0; ks < 2; ++ks)
        aq[ks] = *reinterpret_cast<const short8*>(Qh + (qr0 + l15) * DK + ks * 32 + lg * 8);
    f32x4 o[4] = {};
    float zloc = 0.0f;
    unsigned short* Pw = lds + 8192 + w * 1024;  // [16][64] swizzled
    int kc_t = tid >> 3;        // K stage: row 0..63
    int kc_c8 = (tid & 7) * 8;  //          col chunk
    int vc_t = tid & 63;        // V stage: t 0..63
    int vc_vg = tid >> 6;       //          v group 0..7
    for (int t0 = 0; t0 < S_LEN; t0 += 64) {
        // stage K tile [t][k], swizzled
        short8 kv = *reinterpret_cast<const short8*>(Kh + (t0 + kc_t) * DK + kc_c8);
        *reinterpret_cast<short8*>(&lds[kc_t * 64 + (kc_c8 ^ ((kc_t & 7) << 3))]) = kv;
        // stage V transposed [v][t], swizzled
        short8 vv = *reinterpret_cast<const short8*>(Vh + (t0 + vc_t) * DK + vc_vg * 8);
#pragma unroll
        for (int i = 0; i < 8; ++i) {
            int v = vc_vg * 8 + i;
            lds[4096 + v * 64 + (vc_t ^ ((v & 7) << 3))] = (unsigned short)vv[i];
        }
        __syncthreads();
        // S = Q K^T (Q pre-scaled by 1/8)
        f32x4 sacc[4] = {};
#pragma unroll
        for (int ks = 0; ks < 2; ++ks) {
#pragma unroll
            for (int tb = 0; tb < 4; ++tb) {
                int t = tb * 16 + l15;
                short8 bk = *reinterpret_cast<const short8*>(
                    &lds[t * 64 + ((ks * 32 + lg * 8) ^ ((t & 7) << 3))]);
                sacc[tb] = __builtin_amdgcn_mfma_f32_16x16x32_bf16(aq[ks], bk, sacc[tb], 0, 0, 0);
            }
        }
        // exp, Z partial, P -> LDS (bf16)
#pragma unroll
        for (int tb = 0; tb < 4; ++tb) {
#pragma unroll
            for (int r = 0; r < 4; ++r) {
                float p = __expf(sacc[tb][r]);
                zloc += p;
                int ql = lg * 4 + r;
                int t = tb * 16 + l15;
                Pw[ql * 64 + (t ^ ((ql & 7) << 3))] = f2bf(p);
            }
        }
        // O += P V
#pragma unroll
        for (int ks2 = 0; ks2 < 2; ++ks2) {
            short8 pa = *reinterpret_cast<const short8*>(
                &Pw[l15 * 64 + ((ks2 * 32 + lg * 8) ^ ((l15 & 7) << 3))]);
#pragma unroll
            for (int vb = 0; vb < 4; ++vb) {
                int v = vb * 16 + l15;
                short8 bv = *reinterpret_cast<const short8*>(
                    &lds[4096 + v * 64 + ((ks2 * 32 + lg * 8) ^ ((v & 7) << 3))]);
                o[vb] = __builtin_amdgcn_mfma_f32_16x16x32_bf16(pa, bv, o[vb], 0, 0, 0);
            }
        }
        __syncthreads();
    }
    // write unnormalized concat[s][h*64+v] as bf16
#pragma unroll
    for (int vb = 0; vb < 4; ++vb)
#pragma unroll
        for (int r = 0; r < 4; ++r)
            concat[(qr0 + lg * 4 + r) * DMODEL + h * DK + vb * 16 + l15] = f2bf(o[vb][r]);
    // Z: wave reduce + one atomic per wave
#pragma unroll
    for (int off = 32; off > 0; off >>= 1)
        zloc += __shfl_xor(zloc, off, 64);
    if (l == 0) atomicAdd(Z, zloc);
}

// ---------------- output projection GEMM (x 1/Z) ----------------
__global__ __launch_bounds__(256) void out_gemm_kernel(
    const unsigned short* __restrict__ A,   // concat bf16 [4096][512]
    const unsigned short* __restrict__ BT,  // woT bf16 [m][hv]
    const float* __restrict__ Z,
    float* __restrict__ Cout) {
    int tid = threadIdx.x;
    int w = tid >> 6, l = tid & 63;
    int l15 = l & 15, lg = l >> 4;
    int mb = blockIdx.x, nb0 = blockIdx.y * 64;
    float invZ = 1.0f / *Z;
    int row_a = mb * 64 + w * 16 + l15;
    f32x4 acc[4] = {};
    for (int ks = 0; ks < DMODEL; ks += 32) {
        short8 a = *reinterpret_cast<const short8*>(A + row_a * DMODEL + ks + lg * 8);
#pragma unroll
        for (int nb = 0; nb < 4; ++nb) {
            short8 b = *reinterpret_cast<const short8*>(BT + (nb0 + nb * 16 + l15) * DMODEL + ks + lg * 8);
            acc[nb] = __builtin_amdgcn_mfma_f32_16x16x32_bf16(a, b, acc[nb], 0, 0, 0);
        }
    }
    int row_c = mb * 64 + w * 16 + lg * 4;
#pragma unroll
    for (int nb = 0; nb < 4; ++nb)
#pragma unroll
        for (int r = 0; r < 4; ++r)
            Cout[(row_c + r) * DMODEL + nb0 + nb * 16 + l15] = acc[nb][r] * invZ;
}

// ---------------- launcher ----------------

extern "C" void kernel_launch(void* const* d_in, const int* in_sizes, int n_in,
                              void* d_out, int out_size, void* d_ws, size_t ws_size,
                              hipStream_t stream) {
    const float* emb = (const float*)d_in[0];
    const float* wq = (const float*)d_in[1];
    const float* wk = (const float*)d_in[2];
    const float* wv = (const float*)d_in[3];
    const float* wo = (const float*)d_in[4];
    float* out = (float*)d_out;
    char* ws = (char*)d_ws;
    unsigned short* embB = (unsigned short*)(ws);             // 4 MB
    unsigned short* wqT  = (unsigned short*)(ws + 4194304);   // 512 KB
    unsigned short* wkT  = (unsigned short*)(ws + 4718592);
    unsigned short* wvT  = (unsigned short*)(ws + 5242880);
    unsigned short* woT  = (unsigned short*)(ws + 5767168);
    unsigned short* Qb   = (unsigned short*)(ws + 6291456);   // 4 MB each
    unsigned short* Kb   = (unsigned short*)(ws + 10485760);
    unsigned short* Vb   = (unsigned short*)(ws + 14680064);
    unsigned short* cc   = (unsigned short*)(ws + 18874368);  // 4 MB
    float* Z             = (float*)(ws + 23068672);

    cast_bf16_kernel<<<2048, 256, 0, stream>>>(emb, embB, 524288);
    transpose_w_kernel<<<1024, 256, 0, stream>>>(wq, wqT, 512, 64, 262144);
    transpose_w_kernel<<<1024, 256, 0, stream>>>(wk, wkT, 512, 64, 262144);
    transpose_w_kernel<<<1024, 256, 0, stream>>>(wv, wvT, 512, 64, 262144);
    transpose_w_kernel<<<1024, 256, 0, stream>>>(wo, woT, 512, 512, 262144);
    zero_kernel<<<1, 1, 0, stream>>>(Z);
    proj_gemm_kernel<<<dim3(64, 24), 256, 0, stream>>>(embB, wqT, wkT, wvT, Qb, Kb, Vb);
    attn_kernel<<<dim3(32, 8), 512, 0, stream>>>(Qb, Kb, Vb, cc, Z);
    out_gemm_kernel<<<dim3(64, 8), 256, 0, stream>>>(cc, woT, Z, out);
}